// Round 3
// baseline (344.243 us; speedup 1.0000x reference)
//
#include <hip/hip_runtime.h>

#define S_TOT 32768
#define C_IN 192
#define NB 2
#define NH 8
#define DH 64
#define ATT_SCALE 0.125f

// workspace layout (float offsets)
#define G_OFF   0
#define G_SZ    (NB * C_IN * C_IN)        // 73728
#define T_OFF   (G_OFF + G_SZ)
#define T_SZ    (NB * 512 * C_IN)         // 196608
#define M_OFF   (T_OFF + T_SZ)
#define M_SZ    (NB * 512 * C_IN)         // 196608
#define W_OFF   (M_OFF + M_SZ)
#define W_SZ    (NB * C_IN * C_IN)        // 73728

// ---------------- Gram: G[b] = X_b * X_b^T, read-each-element-once ----------------
// grid (128, NB), block 512. Each block owns a K-slice of 256 (8 chunks of 32),
// stages the full 192-row x 32-k chunk in LDS (single buffer = both operands),
// accumulates 72 partials/thread (rows tyy+32*rr, cols tx+16*cc), atomicAdd at end.
#define GR_CH 8
#define GR_BK 32
__global__ __launch_bounds__(512, 2) void gram_kernel(const float* __restrict__ x,
                                                      float* __restrict__ G) {
    int b     = blockIdx.y;
    int kbase = blockIdx.x * (GR_CH * GR_BK);   // 256-wide K slice

    __shared__ float Ls[GR_BK][196];

    int tid = threadIdx.x;
    int tx  = tid & 15;       // col group: cols tx + 16*cc
    int tyy = tid >> 4;       // 0..31,  rows tyy + 32*rr

    const float* xb = x + (size_t)b * C_IN * S_TOT;

    // loader mapping: float4 id = tid + 512*q (q=0..2); id -> row c = id>>3, kq = id&7
    int lc[3], lkq[3];
#pragma unroll
    for (int q = 0; q < 3; q++) { int id = tid + 512 * q; lc[q] = id >> 3; lkq[q] = id & 7; }

    float acc[6][12] = {};
    float4 pf[3];

#pragma unroll
    for (int q = 0; q < 3; q++)
        pf[q] = *(const float4*)(xb + (size_t)lc[q] * S_TOT + kbase + lkq[q] * 4);

    for (int ch = 0; ch < GR_CH; ++ch) {
        __syncthreads();
#pragma unroll
        for (int q = 0; q < 3; q++) {
            Ls[lkq[q] * 4 + 0][lc[q]] = pf[q].x;
            Ls[lkq[q] * 4 + 1][lc[q]] = pf[q].y;
            Ls[lkq[q] * 4 + 2][lc[q]] = pf[q].z;
            Ls[lkq[q] * 4 + 3][lc[q]] = pf[q].w;
        }
        __syncthreads();
        if (ch + 1 < GR_CH) {
            int k0 = kbase + (ch + 1) * GR_BK;
#pragma unroll
            for (int q = 0; q < 3; q++)
                pf[q] = *(const float4*)(xb + (size_t)lc[q] * S_TOT + k0 + lkq[q] * 4);
        }
#pragma unroll
        for (int kk = 0; kk < GR_BK; ++kk) {
            float a[6], bb[12];
#pragma unroll
            for (int rr = 0; rr < 6; ++rr)  a[rr] = Ls[kk][tyy + 32 * rr];
#pragma unroll
            for (int cc = 0; cc < 12; ++cc) bb[cc] = Ls[kk][tx + 16 * cc];
#pragma unroll
            for (int rr = 0; rr < 6; ++rr)
#pragma unroll
                for (int cc = 0; cc < 12; ++cc)
                    acc[rr][cc] = fmaf(a[rr], bb[cc], acc[rr][cc]);
        }
    }

    float* Gb = G + b * C_IN * C_IN;
#pragma unroll
    for (int rr = 0; rr < 6; ++rr)
#pragma unroll
        for (int cc = 0; cc < 12; ++cc)
            atomicAdd(&Gb[(tyy + 32 * rr) * C_IN + tx + 16 * cc], acc[rr][cc]);
}

// ---------------- generic 64x64-tile GEMM: C[b] = A[b] (MxK) * B[b] (KxN) ----------------
__global__ __launch_bounds__(256) void gemm64_kernel(const float* __restrict__ A,
                                                     const float* __restrict__ B,
                                                     float* __restrict__ C,
                                                     int K, int N,
                                                     long aStride, long bStride, long cStride) {
    int mi0 = blockIdx.x * 64;
    int nj0 = blockIdx.y * 64;
    int b   = blockIdx.z;

    __shared__ float As[16][68];
    __shared__ float Bs[16][68];

    int tid = threadIdx.x;
    int tx = tid & 15, ty = tid >> 4;
    int lrow = tid >> 2, lk = (tid & 3) * 4;
    int ldk = tid >> 4, ldn = (tid & 15) * 4;

    const float* Ab = A + b * aStride;
    const float* Bb = B + b * bStride;

    float acc[4][4] = {};

    for (int k0 = 0; k0 < K; k0 += 16) {
        float4 av = *(const float4*)(Ab + (size_t)(mi0 + lrow) * K + k0 + lk);
        float4 bv = *(const float4*)(Bb + (size_t)(k0 + ldk) * N + nj0 + ldn);
        __syncthreads();
        As[lk + 0][lrow] = av.x; As[lk + 1][lrow] = av.y;
        As[lk + 2][lrow] = av.z; As[lk + 3][lrow] = av.w;
        *(float4*)&Bs[ldk][ldn] = bv;
        __syncthreads();
#pragma unroll
        for (int kk = 0; kk < 16; kk++) {
            float4 a = *(const float4*)&As[kk][ty * 4];
            float4 bb = *(const float4*)&Bs[kk][tx * 4];
            acc[0][0] += a.x * bb.x; acc[0][1] += a.x * bb.y; acc[0][2] += a.x * bb.z; acc[0][3] += a.x * bb.w;
            acc[1][0] += a.y * bb.x; acc[1][1] += a.y * bb.y; acc[1][2] += a.y * bb.z; acc[1][3] += a.y * bb.w;
            acc[2][0] += a.z * bb.x; acc[2][1] += a.z * bb.y; acc[2][2] += a.z * bb.z; acc[2][3] += a.z * bb.w;
            acc[3][0] += a.w * bb.x; acc[3][1] += a.w * bb.y; acc[3][2] += a.w * bb.z; acc[3][3] += a.w * bb.w;
        }
    }

    float* Cb = C + b * cStride;
#pragma unroll
    for (int r = 0; r < 4; r++) {
        float4 v = { acc[r][0], acc[r][1], acc[r][2], acc[r][3] };
        *(float4*)(Cb + (size_t)(mi0 + ty * 4 + r) * N + nj0 + tx * 4) = v;
    }
}

// ---------------- fused: sim = T_h wk_h^T * SCALE -> softmax -> M_h = attn * wv_h ----------------
__global__ __launch_bounds__(256) void simsoftm_kernel(const float* __restrict__ T,
                                                       const float* __restrict__ wk,
                                                       const float* __restrict__ wv,
                                                       float* __restrict__ M) {
    int b = blockIdx.x, h = blockIdx.y;

    __shared__ float As[16][68];
    __shared__ float Bs[16][68];
    __shared__ float At[64][68];   // attn TRANSPOSED: At[j][i]

    int tid = threadIdx.x;
    int tx = tid & 15, ty = tid >> 4;
    int lrow = tid >> 2, lk = (tid & 3) * 4;
    int ldk = tid >> 4, ldn = (tid & 15) * 4;

    const float* Th  = T + (size_t)b * 512 * C_IN + (size_t)(h * 64) * C_IN;
    const float* wkh = wk + (size_t)(h * 64) * C_IN;
    const float* wvh = wv + (size_t)(h * 64) * C_IN;

    float acc[4][4] = {};
    for (int k0 = 0; k0 < C_IN; k0 += 16) {
        float4 av = *(const float4*)(Th  + (size_t)lrow * C_IN + k0 + lk);
        float4 bv = *(const float4*)(wkh + (size_t)lrow * C_IN + k0 + lk);
        __syncthreads();
        As[lk + 0][lrow] = av.x; As[lk + 1][lrow] = av.y;
        As[lk + 2][lrow] = av.z; As[lk + 3][lrow] = av.w;
        Bs[lk + 0][lrow] = bv.x; Bs[lk + 1][lrow] = bv.y;
        Bs[lk + 2][lrow] = bv.z; Bs[lk + 3][lrow] = bv.w;
        __syncthreads();
#pragma unroll
        for (int kk = 0; kk < 16; kk++) {
            float4 a = *(const float4*)&As[kk][ty * 4];
            float4 bb = *(const float4*)&Bs[kk][tx * 4];
            acc[0][0] += a.x * bb.x; acc[0][1] += a.x * bb.y; acc[0][2] += a.x * bb.z; acc[0][3] += a.x * bb.w;
            acc[1][0] += a.y * bb.x; acc[1][1] += a.y * bb.y; acc[1][2] += a.y * bb.z; acc[1][3] += a.y * bb.w;
            acc[2][0] += a.z * bb.x; acc[2][1] += a.z * bb.y; acc[2][2] += a.z * bb.z; acc[2][3] += a.z * bb.w;
            acc[3][0] += a.w * bb.x; acc[3][1] += a.w * bb.y; acc[3][2] += a.w * bb.z; acc[3][3] += a.w * bb.w;
        }
    }

#pragma unroll
    for (int r = 0; r < 4; r++) {
        float s0 = acc[r][0] * ATT_SCALE, s1 = acc[r][1] * ATT_SCALE;
        float s2 = acc[r][2] * ATT_SCALE, s3 = acc[r][3] * ATT_SCALE;
        float mx = fmaxf(fmaxf(s0, s1), fmaxf(s2, s3));
        mx = fmaxf(mx, __shfl_xor(mx, 1));
        mx = fmaxf(mx, __shfl_xor(mx, 2));
        mx = fmaxf(mx, __shfl_xor(mx, 4));
        mx = fmaxf(mx, __shfl_xor(mx, 8));
        float e0 = __expf(s0 - mx), e1 = __expf(s1 - mx);
        float e2 = __expf(s2 - mx), e3 = __expf(s3 - mx);
        float sum = (e0 + e1) + (e2 + e3);
        sum += __shfl_xor(sum, 1);
        sum += __shfl_xor(sum, 2);
        sum += __shfl_xor(sum, 4);
        sum += __shfl_xor(sum, 8);
        float inv = 1.0f / sum;
        At[tx * 4 + 0][ty * 4 + r] = e0 * inv;
        At[tx * 4 + 1][ty * 4 + r] = e1 * inv;
        At[tx * 4 + 2][ty * 4 + r] = e2 * inv;
        At[tx * 4 + 3][ty * 4 + r] = e3 * inv;
    }

    float* Mb = M + (size_t)b * 512 * C_IN + (size_t)(h * 64) * C_IN;
    for (int nj = 0; nj < C_IN; nj += 64) {
        float acc2[4][4] = {};
        for (int j0 = 0; j0 < 64; j0 += 16) {
            float4 bv = *(const float4*)(wvh + (size_t)(j0 + ldk) * C_IN + nj + ldn);
            __syncthreads();
            *(float4*)&Bs[ldk][ldn] = bv;
            __syncthreads();
#pragma unroll
            for (int kk = 0; kk < 16; kk++) {
                float4 a = *(const float4*)&At[j0 + kk][ty * 4];
                float4 bb = *(const float4*)&Bs[kk][tx * 4];
                acc2[0][0] += a.x * bb.x; acc2[0][1] += a.x * bb.y; acc2[0][2] += a.x * bb.z; acc2[0][3] += a.x * bb.w;
                acc2[1][0] += a.y * bb.x; acc2[1][1] += a.y * bb.y; acc2[1][2] += a.y * bb.z; acc2[1][3] += a.y * bb.w;
                acc2[2][0] += a.z * bb.x; acc2[2][1] += a.z * bb.y; acc2[2][2] += a.z * bb.z; acc2[2][3] += a.z * bb.w;
                acc2[3][0] += a.w * bb.x; acc2[3][1] += a.w * bb.y; acc2[3][2] += a.w * bb.z; acc2[3][3] += a.w * bb.w;
            }
        }
#pragma unroll
        for (int r = 0; r < 4; r++) {
            float4 v = { acc2[r][0], acc2[r][1], acc2[r][2], acc2[r][3] };
            *(float4*)(Mb + (size_t)(ty * 4 + r) * C_IN + nj + tx * 4) = v;
        }
    }
}

// ---------------- out[b][o][s] = sum_c W[b][o][c] * x[b][c][s] + bo[o] ----------------
// grid (3, 128, NB), block 256. 64x256 tile, micro 4x16 (cols tx*4 + 64u),
// register-prefetch pipeline, conflict-free Xs reads.
__global__ __launch_bounds__(256) void final_kernel(const float* __restrict__ x,
                                                    const float* __restrict__ Wm,
                                                    const float* __restrict__ bo,
                                                    float* __restrict__ out) {
    int m0 = blockIdx.x * 64;
    int n0 = blockIdx.y * 256;
    int b  = blockIdx.z;

    __shared__ float As[16][68];
    __shared__ float Xs[16][260];

    int tid = threadIdx.x;
    int tx = tid & 15, ty = tid >> 4;
    int lrow = tid >> 2, lk = (tid & 3) * 4;          // A loader
    // X loader: float4 id = tid + 256*q (q=0..3): xrow = id>>6, xcol = (id&63)*4
    int xrow[4], xcol[4];
#pragma unroll
    for (int q = 0; q < 4; q++) { int id = tid + 256 * q; xrow[q] = id >> 6; xcol[q] = (id & 63) * 4; }

    const float* Wb = Wm + b * C_IN * C_IN;
    const float* xb = x + (size_t)b * C_IN * S_TOT;

    float acc[4][16] = {};
    float4 apf;
    float4 xpf[4];

    apf = *(const float4*)(Wb + (size_t)(m0 + lrow) * C_IN + lk);
#pragma unroll
    for (int q = 0; q < 4; q++)
        xpf[q] = *(const float4*)(xb + (size_t)xrow[q] * S_TOT + n0 + xcol[q]);

    for (int kc = 0; kc < 12; ++kc) {
        __syncthreads();
        As[lk + 0][lrow] = apf.x; As[lk + 1][lrow] = apf.y;
        As[lk + 2][lrow] = apf.z; As[lk + 3][lrow] = apf.w;
#pragma unroll
        for (int q = 0; q < 4; q++) *(float4*)&Xs[xrow[q]][xcol[q]] = xpf[q];
        __syncthreads();
        if (kc + 1 < 12) {
            int k0 = (kc + 1) * 16;
            apf = *(const float4*)(Wb + (size_t)(m0 + lrow) * C_IN + k0 + lk);
#pragma unroll
            for (int q = 0; q < 4; q++)
                xpf[q] = *(const float4*)(xb + (size_t)(k0 + xrow[q]) * S_TOT + n0 + xcol[q]);
        }
#pragma unroll
        for (int kk = 0; kk < 16; kk++) {
            float4 a = *(const float4*)&As[kk][ty * 4];
#pragma unroll
            for (int u = 0; u < 4; u++) {
                float4 xv = *(const float4*)&Xs[kk][tx * 4 + 64 * u];
                acc[0][u * 4 + 0] = fmaf(a.x, xv.x, acc[0][u * 4 + 0]);
                acc[0][u * 4 + 1] = fmaf(a.x, xv.y, acc[0][u * 4 + 1]);
                acc[0][u * 4 + 2] = fmaf(a.x, xv.z, acc[0][u * 4 + 2]);
                acc[0][u * 4 + 3] = fmaf(a.x, xv.w, acc[0][u * 4 + 3]);
                acc[1][u * 4 + 0] = fmaf(a.y, xv.x, acc[1][u * 4 + 0]);
                acc[1][u * 4 + 1] = fmaf(a.y, xv.y, acc[1][u * 4 + 1]);
                acc[1][u * 4 + 2] = fmaf(a.y, xv.z, acc[1][u * 4 + 2]);
                acc[1][u * 4 + 3] = fmaf(a.y, xv.w, acc[1][u * 4 + 3]);
                acc[2][u * 4 + 0] = fmaf(a.z, xv.x, acc[2][u * 4 + 0]);
                acc[2][u * 4 + 1] = fmaf(a.z, xv.y, acc[2][u * 4 + 1]);
                acc[2][u * 4 + 2] = fmaf(a.z, xv.z, acc[2][u * 4 + 2]);
                acc[2][u * 4 + 3] = fmaf(a.z, xv.w, acc[2][u * 4 + 3]);
                acc[3][u * 4 + 0] = fmaf(a.w, xv.x, acc[3][u * 4 + 0]);
                acc[3][u * 4 + 1] = fmaf(a.w, xv.y, acc[3][u * 4 + 1]);
                acc[3][u * 4 + 2] = fmaf(a.w, xv.z, acc[3][u * 4 + 2]);
                acc[3][u * 4 + 3] = fmaf(a.w, xv.w, acc[3][u * 4 + 3]);
            }
        }
    }

#pragma unroll
    for (int r = 0; r < 4; r++) {
        int m = m0 + ty * 4 + r;
        float bias = bo[m];
        float* op = out + ((size_t)b * C_IN + m) * S_TOT + n0;
#pragma unroll
        for (int u = 0; u < 4; u++) {
            float4 v = { acc[r][u * 4 + 0] + bias, acc[r][u * 4 + 1] + bias,
                         acc[r][u * 4 + 2] + bias, acc[r][u * 4 + 3] + bias };
            *(float4*)(op + tx * 4 + 64 * u) = v;
        }
    }
}

extern "C" void kernel_launch(void* const* d_in, const int* in_sizes, int n_in,
                              void* d_out, int out_size, void* d_ws, size_t ws_size,
                              hipStream_t stream) {
    const float* x  = (const float*)d_in[0];
    const float* wq = (const float*)d_in[1];
    const float* wk = (const float*)d_in[2];
    const float* wv = (const float*)d_in[3];
    const float* wo = (const float*)d_in[4];
    const float* bo = (const float*)d_in[5];
    float* out = (float*)d_out;
    float* ws  = (float*)d_ws;

    float* gG = ws + G_OFF;
    float* gT = ws + T_OFF;
    float* gM = ws + M_OFF;
    float* gW = ws + W_OFF;

    hipMemsetAsync(gG, 0, G_SZ * sizeof(float), stream);
    gram_kernel<<<dim3(128, NB), 512, 0, stream>>>(x, gG);

    // T[b] = wq (512x192) * G_b (192x192)
    gemm64_kernel<<<dim3(8, 3, NB), 256, 0, stream>>>(
        wq, gG, gT, C_IN, C_IN, 0L, (long)(C_IN * C_IN), (long)(512 * C_IN));

    simsoftm_kernel<<<dim3(NB, NH), 256, 0, stream>>>(gT, wk, wv, gM);

    // W[b] = wo (192x512) * M_b (512x192)
    gemm64_kernel<<<dim3(3, 3, NB), 256, 0, stream>>>(
        wo, gM, gW, 512, C_IN, 0L, (long)(512 * C_IN), (long)(C_IN * C_IN));

    final_kernel<<<dim3(3, 128, NB), 256, 0, stream>>>(x, gW, bo, out);
}